// Round 16
// baseline (310.603 us; speedup 1.0000x reference)
//
#include <hip/hip_runtime.h>

#define NN 100000
#define NNP 100352               // 98 * 1024 (padded node count)
#define NE 1280000
#define K_FEAT 500
#define K_TEXT 384
#define KP 512
#define H 64
#define BM 64
#define GEMM_GRID 1563           // (NN+BM-1)/BM
#define SCAN_BLOCKS 98
#define NODES_PER_SCAN 1024
#define FUSE_BLOCKS 257
#define SORT_CHUNK 2048
#define NCHUNKS 625              // NE / SORT_CHUNK
#define P2CAP 16384              // LDS staging capacity (edges) per bucket

typedef unsigned short ushort_t;
typedef __attribute__((ext_vector_type(8))) short bf16x8;
typedef __attribute__((ext_vector_type(4))) float f32x4;

template <int V> struct IC { static constexpr int value = V; };

__device__ __forceinline__ ushort_t f2bf(float f) {
    union { float f; unsigned int u; } v; v.f = f;
    unsigned int r = (v.u + 0x7FFFu + ((v.u >> 16) & 1u)) >> 16;  // RNE
    return (ushort_t)r;
}

__device__ __forceinline__ float bf2f(ushort_t u) {
    union { unsigned int i; float f; } v; v.i = ((unsigned int)u) << 16; return v.f;
}

// pack 8 f32 -> 8 bf16 via hardware cvt_pk (RNE)
__device__ __forceinline__ bf16x8 cvt8(float4 a, float4 b) {
    union { bf16x8 v; unsigned int w[4]; } u;
    asm("v_cvt_pk_bf16_f32 %0, %1, %2" : "=v"(u.w[0]) : "v"(a.x), "v"(a.y));
    asm("v_cvt_pk_bf16_f32 %0, %1, %2" : "=v"(u.w[1]) : "v"(a.z), "v"(a.w));
    asm("v_cvt_pk_bf16_f32 %0, %1, %2" : "=v"(u.w[2]) : "v"(b.x), "v"(b.y));
    asm("v_cvt_pk_bf16_f32 %0, %1, %2" : "=v"(u.w[3]) : "v"(b.z), "v"(b.w));
    return u.v;
}

// ---------------- fused preprocessing: weight fusion (blocks < FUSE_BLOCKS) + degree count ----
__global__ void prep_k(const float* __restrict__ wf, const float* __restrict__ bf,
                       const float* __restrict__ wt, const float* __restrict__ bt,
                       const float* __restrict__ w1,
                       ushort_t* __restrict__ WfxT, ushort_t* __restrict__ WtxT,
                       float* __restrict__ bpre,
                       const int* __restrict__ ei, int* __restrict__ deg) {
    if (blockIdx.x >= FUSE_BLOCKS) {
        const int p = ((blockIdx.x - FUSE_BLOCKS) * 256 + threadIdx.x) * 4;
        if (p + 3 < NE) {
            const int4 d = *(const int4*)&ei[NE + p];
            atomicAdd(&deg[d.x], 1);
            atomicAdd(&deg[d.y], 1);
            atomicAdd(&deg[d.z], 1);
            atomicAdd(&deg[d.w], 1);
        }
        return;
    }
    const int idx = blockIdx.x * 256 + threadIdx.x;
    const int T1 = H * KP;
    const int T2 = 2 * T1;
    if (idx < T1) {
        const int c = idx >> 9, k = idx & 511;
        float s = 0.f;
        if (k < K_FEAT) {
            #pragma unroll 8
            for (int u = 0; u < 64; ++u) s = fmaf(wf[k * 64 + u], w1[u * 64 + c], s);
        }
        WfxT[idx] = f2bf(s);
    } else if (idx < T2) {
        const int r = idx - T1;
        const int c = r >> 9, k = r & 511;
        float s = 0.f;
        if (k < K_TEXT) {
            #pragma unroll 8
            for (int u = 0; u < 64; ++u) s = fmaf(wt[k * 64 + u], w1[(64 + u) * 64 + c], s);
        }
        WtxT[r] = f2bf(s);
    } else if (idx < T2 + H) {
        const int j = idx - T2;
        float s = 0.f;
        for (int u = 0; u < 64; ++u) s = fmaf(bf[u], w1[u * 64 + j], s);
        for (int u = 0; u < 64; ++u) s = fmaf(bt[u], w1[(64 + u) * 64 + j], s);
        bpre[j] = s;
    }
}

// ---------------- CSR offsets (partial-scan folded: each block sums deg[0..base) itself) ----
__global__ __launch_bounds__(256)
void offsets_k(const int* __restrict__ deg, int* __restrict__ row_start,
               float* __restrict__ dinv, int* __restrict__ bstart,
               int* __restrict__ bcursor) {
    const int b = blockIdx.x;
    const int base = b * NODES_PER_SCAN;
    const int t = threadIdx.x;
    __shared__ int tsum[256];
    __shared__ int ws[4];
    // global exclusive prefix: sum of deg[0..base), int4-vectorized
    int pre = 0;
    for (int i = t; i < (base >> 2); i += 256) {
        const int4 v = ((const int4*)deg)[i];
        pre += v.x + v.y + v.z + v.w;
    }
    #pragma unroll
    for (int m = 1; m < 64; m <<= 1) pre += __shfl_xor(pre, m, 64);
    if ((t & 63) == 0) ws[t >> 6] = pre;
    __syncthreads();
    const int bp = ws[0] + ws[1] + ws[2] + ws[3];
    // local scan of this block's 1024 nodes
    int loc[4];
    int dg[4];
    int s = 0;
    #pragma unroll
    for (int i = 0; i < 4; ++i) {
        loc[i] = s;
        dg[i] = deg[base + t * 4 + i];          // padded arrays: no guard needed
        s += dg[i];
    }
    tsum[t] = s;
    __syncthreads();
    #pragma unroll
    for (int off = 1; off < 256; off <<= 1) {
        int v = (t >= off) ? tsum[t - off] : 0;
        __syncthreads();
        tsum[t] += v;
        __syncthreads();
    }
    if (t == 0) { bstart[b] = bp; bcursor[b] = bp; if (b == SCAN_BLOCKS - 1) bstart[SCAN_BLOCKS] = NE; }
    const int texcl = (t == 0) ? 0 : tsum[t - 1];
    #pragma unroll
    for (int i = 0; i < 4; ++i) {
        const int n = t * 4 + i;
        const int rs = bp + texcl + loc[i];
        row_start[base + n] = rs;
        dinv[base + n] = rsqrtf((float)dg[i] + 1.0f);
    }
}

// ---------------- FAT kernel: gemm1 (odd blocks) ∥ sort pass-1 binning (even blocks) --------
__global__ __launch_bounds__(256)
void gemm_sort_k(const float* __restrict__ x, const float* __restrict__ txt,
                 const ushort_t* __restrict__ WfxT, const ushort_t* __restrict__ WtxT,
                 const float* __restrict__ bpre, const int* __restrict__ deg,
                 ushort_t* __restrict__ u1b,
                 const int* __restrict__ ei, int* __restrict__ bcursor,
                 int2* __restrict__ pairs) {
    __shared__ float As0[BM * 64], As1[BM * 64];      // 16 KB each, 256B rows, swizzled
    __shared__ ushort_t Bs0[H * 64], Bs1[H * 64];     // 8 KB each, 128B rows, swizzled
    const int b = blockIdx.x;
    const int t = threadIdx.x;

    if ((b & 1) == 0) {
        // ---------------- sort pass-1: LDS-binned bucket append ----------------
        int* hist = (int*)As0;          // [98]
        int* bbase = hist + 128;        // [98]
        for (int chunk = b >> 1; chunk < NCHUNKS; chunk += GEMM_GRID) {
            const int e0 = chunk * SORT_CHUNK + t * 8;
            int4 s0 = *(const int4*)&ei[e0];
            int4 s1 = *(const int4*)&ei[e0 + 4];
            int4 d0 = *(const int4*)&ei[NE + e0];
            int4 d1 = *(const int4*)&ei[NE + e0 + 4];
            const int src[8] = {s0.x, s0.y, s0.z, s0.w, s1.x, s1.y, s1.z, s1.w};
            const int dst[8] = {d0.x, d0.y, d0.z, d0.w, d1.x, d1.y, d1.z, d1.w};
            if (t < 98) hist[t] = 0;
            __syncthreads();
            int bu[8];
            #pragma unroll
            for (int i = 0; i < 8; ++i) {
                bu[i] = dst[i] >> 10;
                atomicAdd(&hist[bu[i]], 1);
            }
            __syncthreads();
            if (t < 98) bbase[t] = atomicAdd(&bcursor[t], hist[t]);
            __syncthreads();
            #pragma unroll
            for (int i = 0; i < 8; ++i) {
                const int pos = atomicAdd(&bbase[bu[i]], 1);
                pairs[pos] = make_int2(src[i], dst[i]);
            }
            __syncthreads();
        }
        return;
    }

    const int wave = t >> 6, lane = t & 63;
    const int row0 = (b >> 1) * BM;
    const int lr = lane & 15, lq = lane >> 4;

    f32x4 acc[4];
    #pragma unroll
    for (int j = 0; j < 4; ++j) acc[j] = (f32x4){0.f, 0.f, 0.f, 0.f};

    auto stageA = [&](char* ldsa, const float* __restrict__ A, const int KD, const int k0) {
        #pragma unroll
        for (int p = 0; p < 4; ++p) {
            const int P = p * 4096 + t * 16;
            const int row = P >> 8;
            const int kk = ((P & 255) ^ ((row & 7) << 4)) >> 2;
            const int gk = min(k0 + kk, KD - 4);
            const int gr = min(row0 + row, NN - 1);
            __builtin_amdgcn_global_load_lds(
                (const __attribute__((address_space(1))) void*)(A + (long)gr * KD + gk),
                (__attribute__((address_space(3))) void*)(ldsa + P), 16, 0, 2 /*NT*/);
        }
    };
    auto stageB = [&](char* ldsb, const ushort_t* __restrict__ WT, const int k0) {
        #pragma unroll
        for (int p = 0; p < 2; ++p) {
            const int P = p * 4096 + t * 16;
            const int row = P >> 7;
            const int kkb = (P & 127) ^ ((row & 7) << 4);
            __builtin_amdgcn_global_load_lds(
                (const __attribute__((address_space(1))) void*)(WT + (long)row * KP + k0 + (kkb >> 1)),
                (__attribute__((address_space(3))) void*)(ldsb + P), 16, 0, 0);
        }
    };
    auto compute = [&](const char* ldsa, const char* ldsb) {
        #pragma unroll
        for (int ks = 0; ks < 2; ++ks) {
            const int ra = wave * 16 + lr;
            const int ka = ks * 128 + lq * 32;
            const int xa = (ra & 7) << 4;
            const float4 c0 = *(const float4*)(ldsa + ra * 256 + (ka ^ xa));
            const float4 c1 = *(const float4*)(ldsa + ra * 256 + ((ka + 16) ^ xa));
            const bf16x8 af = cvt8(c0, c1);
            bf16x8 bfr[4];
            #pragma unroll
            for (int cf = 0; cf < 4; ++cf) {
                const int col = cf * 16 + lr;
                const int kb = ks * 64 + lq * 16;
                bfr[cf] = *(const bf16x8*)(ldsb + col * 128 + (kb ^ ((col & 7) << 4)));
            }
            #pragma unroll
            for (int cf = 0; cf < 4; ++cf)
                acc[cf] = __builtin_amdgcn_mfma_f32_16x16x32_bf16(
                    af, bfr[cf], acc[cf], 0, 0, 0);
        }
    };

    auto phase = [&](const float* __restrict__ A, const ushort_t* __restrict__ WT,
                     auto KD_, auto NT_) {
        constexpr int KD = decltype(KD_)::value;
        constexpr int NT = decltype(NT_)::value;
        stageA((char*)As0, A, KD, 0);  stageB((char*)Bs0, WT, 0);
        stageA((char*)As1, A, KD, 64); stageB((char*)Bs1, WT, 64);
        #pragma unroll
        for (int kt = 0; kt < NT; ++kt) {
            if (kt == NT - 1) asm volatile("s_waitcnt vmcnt(0)" ::: "memory");
            else              asm volatile("s_waitcnt vmcnt(6)" ::: "memory");
            __builtin_amdgcn_s_barrier();        // chunk kt fully landed for all waves
            __builtin_amdgcn_sched_barrier(0);
            if (kt & 1) compute((const char*)As1, (const char*)Bs1);
            else        compute((const char*)As0, (const char*)Bs0);
            __builtin_amdgcn_sched_barrier(0);
            __builtin_amdgcn_s_barrier();        // all waves done reading buf[kt&1]
            if (kt + 2 < NT) {
                if (kt & 1) { stageA((char*)As1, A, KD, (kt + 2) * 64); stageB((char*)Bs1, WT, (kt + 2) * 64); }
                else        { stageA((char*)As0, A, KD, (kt + 2) * 64); stageB((char*)Bs0, WT, (kt + 2) * 64); }
            }
        }
    };

    phase(x, WfxT, IC<K_FEAT>{}, IC<8>{});
    phase(txt, WtxT, IC<K_TEXT>{}, IC<6>{});

    // epilogue: D frag layout col=lane&15, row=(lane>>4)*4+reg; dinv from deg; store bf16
    #pragma unroll
    for (int reg = 0; reg < 4; ++reg) {
        const int r = row0 + wave * 16 + lq * 4 + reg;
        if (r < NN) {
            const float di = rsqrtf((float)deg[r] + 1.0f);
            #pragma unroll
            for (int cf = 0; cf < 4; ++cf) {
                const int c = cf * 16 + lr;
                u1b[(long)r * H + c] = f2bf((acc[cf][reg] + bpre[c]) * di);
            }
        }
    }
}

// ---------------- fused sort pass-2 + layer1: per-bucket LDS sort, gather from LDS ids ------
// 4 blocks per bucket (q = blockIdx&3). Each block redoes the cheap LDS counting sort
// (pairs read is L2-hot, LDS atomics local), then gathers ITS quarter of the bucket's
// nodes with src ids read from LDS (no global src_sorted reads). q==0 streams the
// sorted segment to global linearly for layer2.
__global__ __launch_bounds__(256)
void sl1_k(const int2* __restrict__ pairs, const int* __restrict__ bstart,
           const int* __restrict__ row_start, const int* __restrict__ deg,
           const ushort_t* __restrict__ u1b, const float* __restrict__ dinv,
           const float* __restrict__ b1, const float* __restrict__ w2,
           int* __restrict__ src_sorted, float* __restrict__ u2) {
    __shared__ int lcur[NODES_PER_SCAN];
    __shared__ int lout[P2CAP];
    const int bu = blockIdx.x >> 2;
    const int q = blockIdx.x & 3;
    const int t = threadIdx.x;
    const int r0 = bstart[bu];
    const int r1 = bstart[bu + 1];
    const int nbase = bu << 10;
    #pragma unroll
    for (int i = 0; i < 4; ++i)
        lcur[t * 4 + i] = row_start[nbase + t * 4 + i] - r0;
    __syncthreads();
    for (int pos = r0 + t; pos < r1; pos += 256) {
        const int2 pr = pairs[pos];
        const int p = atomicAdd(&lcur[pr.y & 1023], 1);
        if (p < P2CAP) lout[p] = pr.x;
    }
    __syncthreads();
    if (q == 0) {
        const int n = min(r1 - r0, P2CAP);
        for (int i = t; i < n; i += 256) src_sorted[r0 + i] = lout[i];
    }
    // gather: this block owns nodes [nbase + q*256, +256); 32 groups x 8 iterations
    const int g8 = t >> 3;
    const int c8 = t & 7;
    for (int it = 0; it < 8; ++it) {
        const int node = nbase + q * 256 + it * 32 + g8;
        if (node >= NN) continue;
        const int rs = row_start[node] - r0;     // offset within lout
        const int dg = deg[node];
        float acc8[8];
        {
            const bf16x8 v = *(const bf16x8*)(u1b + (long)node * H + c8 * 8);
            #pragma unroll
            for (int c = 0; c < 8; ++c) acc8[c] = bf2f((ushort_t)v[c]);
        }
        int j = 0;
        for (; j + 4 <= dg; j += 4) {
            const int s0 = lout[rs + j];
            const int s1 = lout[rs + j + 1];
            const int s2 = lout[rs + j + 2];
            const int s3 = lout[rs + j + 3];
            const bf16x8 v0 = *(const bf16x8*)(u1b + (long)s0 * H + c8 * 8);
            const bf16x8 v1 = *(const bf16x8*)(u1b + (long)s1 * H + c8 * 8);
            const bf16x8 v2 = *(const bf16x8*)(u1b + (long)s2 * H + c8 * 8);
            const bf16x8 v3 = *(const bf16x8*)(u1b + (long)s3 * H + c8 * 8);
            #pragma unroll
            for (int c = 0; c < 8; ++c)
                acc8[c] += (bf2f((ushort_t)v0[c]) + bf2f((ushort_t)v1[c]))
                         + (bf2f((ushort_t)v2[c]) + bf2f((ushort_t)v3[c]));
        }
        for (; j < dg; ++j) {
            const int s0 = lout[rs + j];
            const bf16x8 v0 = *(const bf16x8*)(u1b + (long)s0 * H + c8 * 8);
            #pragma unroll
            for (int c = 0; c < 8; ++c) acc8[c] += bf2f((ushort_t)v0[c]);
        }
        const float di = dinv[node];
        float h[8];
        #pragma unroll
        for (int c = 0; c < 8; ++c)
            h[c] = fmaxf(fmaf(di, acc8[c], b1[c8 * 8 + c]), 0.f);
        #pragma unroll
        for (int jj = 0; jj < 7; ++jj) {
            float s = 0.f;
            #pragma unroll
            for (int c = 0; c < 8; ++c)
                s = fmaf(h[c], w2[(c8 * 8 + c) * 7 + jj], s);
            s += __shfl_xor(s, 1, 64);
            s += __shfl_xor(s, 2, 64);
            s += __shfl_xor(s, 4, 64);
            if (c8 == jj) u2[node * 8 + jj] = di * s;
        }
    }
}

// ---------------- layer2: CSR gather-aggregate + final transform ----------------
__global__ __launch_bounds__(256)
void layer2_csr_k(const int* __restrict__ row_start, const int* __restrict__ deg,
                  const int* __restrict__ src_sorted, const float* __restrict__ u2,
                  const float* __restrict__ dinv, const float* __restrict__ b2,
                  float* __restrict__ out) {
    const int t = threadIdx.x;
    const int c = t & 7;
    const int node = blockIdx.x * 32 + (t >> 3);
    if (node >= NN) return;
    const int rs = row_start[node];
    const int dg = deg[node];
    float acc = (c < 7) ? u2[node * 8 + c] : 0.f;   // self
    int j = 0;
    for (; j + 4 <= dg; j += 4) {
        const int s0 = src_sorted[rs + j];
        const int s1 = src_sorted[rs + j + 1];
        const int s2 = src_sorted[rs + j + 2];
        const int s3 = src_sorted[rs + j + 3];
        if (c < 7) {
            acc += u2[s0 * 8 + c];
            acc += u2[s1 * 8 + c];
            acc += u2[s2 * 8 + c];
            acc += u2[s3 * 8 + c];
        }
    }
    for (; j < dg; ++j) {
        const int s = src_sorted[rs + j];
        if (c < 7) acc += u2[s * 8 + c];
    }
    if (c < 7) out[node * 7 + c] = dinv[node] * acc + b2[c];
}

extern "C" void kernel_launch(void* const* d_in, const int* in_sizes, int n_in,
                              void* d_out, int out_size, void* d_ws, size_t ws_size,
                              hipStream_t stream) {
    const float* x      = (const float*)d_in[0];
    const float* txt    = (const float*)d_in[1];
    const int*   ei     = (const int*)d_in[2];
    const float* w_feat = (const float*)d_in[3];
    const float* b_feat = (const float*)d_in[4];
    const float* w_text = (const float*)d_in[5];
    const float* b_text = (const float*)d_in[6];
    const float* w1     = (const float*)d_in[7];
    const float* b1     = (const float*)d_in[8];
    const float* w2     = (const float*)d_in[9];
    const float* b2     = (const float*)d_in[10];
    float* out = (float*)d_out;

    char* p = (char*)d_ws;
    auto alloc = [&](size_t bytes) {
        char* r = p;
        p += (bytes + 255) & ~(size_t)255;
        return r;
    };
    ushort_t* WfxT = (ushort_t*)alloc((size_t)H * KP * 2);
    ushort_t* WtxT = (ushort_t*)alloc((size_t)H * KP * 2);
    float* bpre = (float*)alloc(H * 4);
    int*   deg  = (int*)alloc((size_t)NNP * 4);
    float* dinv = (float*)alloc((size_t)NNP * 4);
    int*   row_start = (int*)alloc((size_t)NNP * 4);
    int*   bstart    = (int*)alloc((size_t)(SCAN_BLOCKS + 1) * 4);
    int*   bcursor   = (int*)alloc((size_t)SCAN_BLOCKS * 4);
    int2*  pairs     = (int2*)alloc((size_t)NE * 8);
    int*   src_sorted = (int*)alloc((size_t)NE * 4);
    ushort_t* u1b = (ushort_t*)alloc((size_t)NN * H * 2);
    float* u2   = (float*)alloc((size_t)NN * 8 * 4);

    hipMemsetAsync(deg, 0, (size_t)NNP * 4, stream);

    const int deg_blocks = NE / 4 / 256;   // 1250
    prep_k<<<FUSE_BLOCKS + deg_blocks, 256, 0, stream>>>(w_feat, b_feat, w_text, b_text, w1,
                                                         WfxT, WtxT, bpre, ei, deg);
    offsets_k<<<SCAN_BLOCKS, 256, 0, stream>>>(deg, row_start, dinv, bstart, bcursor);
    gemm_sort_k<<<2 * GEMM_GRID, 256, 0, stream>>>(x, txt, WfxT, WtxT, bpre, deg, u1b,
                                                   ei, bcursor, pairs);
    sl1_k<<<SCAN_BLOCKS * 4, 256, 0, stream>>>(pairs, bstart, row_start, deg, u1b,
                                               dinv, b1, w2, src_sorted, u2);
    layer2_csr_k<<<(NN + 31) / 32, 256, 0, stream>>>(row_start, deg, src_sorted, u2,
                                                     dinv, b2, out);
}

// Round 17
// 254.539 us; speedup vs baseline: 1.2203x; 1.2203x over previous
//
#include <hip/hip_runtime.h>

#define NN 100000
#define NNP 100352               // 392 * 256 (padded node count)
#define NE 1280000
#define K_FEAT 500
#define K_TEXT 384
#define KP 512
#define H 64
#define BM 64
#define GEMM_GRID 1563           // (NN+BM-1)/BM
#define SCAN_BLOCKS 98
#define NODES_PER_SCAN 1024
#define FUSE_BLOCKS 257
#define SORT_CHUNK 2048
#define NCHUNKS 625              // NE / SORT_CHUNK
#define BUCKETS 392              // 256-node dst buckets
#define BCAP 4096                // static region capacity per bucket (mean 3265, +14 sigma)

typedef unsigned short ushort_t;
typedef __attribute__((ext_vector_type(8))) short bf16x8;
typedef __attribute__((ext_vector_type(4))) float f32x4;

template <int V> struct IC { static constexpr int value = V; };

__device__ __forceinline__ ushort_t f2bf(float f) {
    union { float f; unsigned int u; } v; v.f = f;
    unsigned int r = (v.u + 0x7FFFu + ((v.u >> 16) & 1u)) >> 16;  // RNE
    return (ushort_t)r;
}

__device__ __forceinline__ float bf2f(ushort_t u) {
    union { unsigned int i; float f; } v; v.i = ((unsigned int)u) << 16; return v.f;
}

// pack 8 f32 -> 8 bf16 via hardware cvt_pk (RNE)
__device__ __forceinline__ bf16x8 cvt8(float4 a, float4 b) {
    union { bf16x8 v; unsigned int w[4]; } u;
    asm("v_cvt_pk_bf16_f32 %0, %1, %2" : "=v"(u.w[0]) : "v"(a.x), "v"(a.y));
    asm("v_cvt_pk_bf16_f32 %0, %1, %2" : "=v"(u.w[1]) : "v"(a.z), "v"(a.w));
    asm("v_cvt_pk_bf16_f32 %0, %1, %2" : "=v"(u.w[2]) : "v"(b.x), "v"(b.y));
    asm("v_cvt_pk_bf16_f32 %0, %1, %2" : "=v"(u.w[3]) : "v"(b.z), "v"(b.w));
    return u.v;
}

// ---------------- preprocessing: weight fusion only (+ bcursor static-region init) ----------
__global__ void prep_k(const float* __restrict__ wf, const float* __restrict__ bf,
                       const float* __restrict__ wt, const float* __restrict__ bt,
                       const float* __restrict__ w1,
                       ushort_t* __restrict__ WfxT, ushort_t* __restrict__ WtxT,
                       float* __restrict__ bpre, int* __restrict__ bcursor) {
    if (blockIdx.x == 0) {
        for (int i = threadIdx.x; i < BUCKETS; i += 256) bcursor[i] = i * BCAP;
    }
    const int idx = blockIdx.x * 256 + threadIdx.x;
    const int T1 = H * KP;
    const int T2 = 2 * T1;
    if (idx < T1) {
        const int c = idx >> 9, k = idx & 511;
        float s = 0.f;
        if (k < K_FEAT) {
            #pragma unroll 8
            for (int u = 0; u < 64; ++u) s = fmaf(wf[k * 64 + u], w1[u * 64 + c], s);
        }
        WfxT[idx] = f2bf(s);
    } else if (idx < T2) {
        const int r = idx - T1;
        const int c = r >> 9, k = r & 511;
        float s = 0.f;
        if (k < K_TEXT) {
            #pragma unroll 8
            for (int u = 0; u < 64; ++u) s = fmaf(wt[k * 64 + u], w1[(64 + u) * 64 + c], s);
        }
        WtxT[r] = f2bf(s);
    } else if (idx < T2 + H) {
        const int j = idx - T2;
        float s = 0.f;
        for (int u = 0; u < 64; ++u) s = fmaf(bf[u], w1[u * 64 + j], s);
        for (int u = 0; u < 64; ++u) s = fmaf(bt[u], w1[(64 + u) * 64 + j], s);
        bpre[j] = s;
    }
}

// ---------------- CSR offsets from deg (runs AFTER the fat kernel) ----------
__global__ __launch_bounds__(256)
void offsets_k(const int* __restrict__ deg, int* __restrict__ row_start,
               float* __restrict__ dinv) {
    const int b = blockIdx.x;
    const int base = b * NODES_PER_SCAN;
    const int t = threadIdx.x;
    __shared__ int tsum[256];
    __shared__ int ws[4];
    // global exclusive prefix: sum of deg[0..base), int4-vectorized
    int pre = 0;
    for (int i = t; i < (base >> 2); i += 256) {
        const int4 v = ((const int4*)deg)[i];
        pre += v.x + v.y + v.z + v.w;
    }
    #pragma unroll
    for (int m = 1; m < 64; m <<= 1) pre += __shfl_xor(pre, m, 64);
    if ((t & 63) == 0) ws[t >> 6] = pre;
    __syncthreads();
    const int bp = ws[0] + ws[1] + ws[2] + ws[3];
    int loc[4];
    int dg[4];
    int s = 0;
    #pragma unroll
    for (int i = 0; i < 4; ++i) {
        loc[i] = s;
        dg[i] = deg[base + t * 4 + i];          // padded arrays: no guard needed
        s += dg[i];
    }
    tsum[t] = s;
    __syncthreads();
    #pragma unroll
    for (int off = 1; off < 256; off <<= 1) {
        int v = (t >= off) ? tsum[t - off] : 0;
        __syncthreads();
        tsum[t] += v;
        __syncthreads();
    }
    const int texcl = (t == 0) ? 0 : tsum[t - 1];
    #pragma unroll
    for (int i = 0; i < 4; ++i) {
        const int n = t * 4 + i;
        const int rs = bp + texcl + loc[i];
        row_start[base + n] = rs;
        dinv[base + n] = rsqrtf((float)dg[i] + 1.0f);
    }
}

// ---------------- FAT kernel: gemm1 (odd) ∥ sort p1 binning + deg count (even) --------------
// gemm1: u1b[N,64] = bf16(x@Wfx + txt@Wtx + bpre)  -- UNSCALED (dinv applied in layer1),
// so gemm has no deg dependency. sort-p1 bins edges by dst>>8 into STATIC bucket regions
// (b*BCAP base -> no CSR dependency) and counts per-node deg -- all hidden under gemm.
__global__ __launch_bounds__(256)
void gemm_sort_k(const float* __restrict__ x, const float* __restrict__ txt,
                 const ushort_t* __restrict__ WfxT, const ushort_t* __restrict__ WtxT,
                 const float* __restrict__ bpre, ushort_t* __restrict__ u1b,
                 const int* __restrict__ ei, int* __restrict__ bcursor,
                 int* __restrict__ deg, int2* __restrict__ pairs) {
    __shared__ float As0[BM * 64], As1[BM * 64];      // 16 KB each, 256B rows, swizzled
    __shared__ ushort_t Bs0[H * 64], Bs1[H * 64];     // 8 KB each, 128B rows, swizzled
    const int b = blockIdx.x;
    const int t = threadIdx.x;

    if ((b & 1) == 0) {
        // ---------------- sort pass-1: LDS-binned static-region append + deg ----------------
        int* hist = (int*)As0;          // [BUCKETS]
        int* bbase = hist + 512;        // [BUCKETS]
        for (int chunk = b >> 1; chunk < NCHUNKS; chunk += GEMM_GRID) {
            const int e0 = chunk * SORT_CHUNK + t * 8;
            int4 s0 = *(const int4*)&ei[e0];
            int4 s1 = *(const int4*)&ei[e0 + 4];
            int4 d0 = *(const int4*)&ei[NE + e0];
            int4 d1 = *(const int4*)&ei[NE + e0 + 4];
            const int src[8] = {s0.x, s0.y, s0.z, s0.w, s1.x, s1.y, s1.z, s1.w};
            const int dst[8] = {d0.x, d0.y, d0.z, d0.w, d1.x, d1.y, d1.z, d1.w};
            for (int i = t; i < BUCKETS; i += 256) hist[i] = 0;
            __syncthreads();
            int bu[8];
            #pragma unroll
            for (int i = 0; i < 8; ++i) {
                bu[i] = dst[i] >> 8;
                atomicAdd(&hist[bu[i]], 1);
                atomicAdd(&deg[dst[i]], 1);
            }
            __syncthreads();
            for (int i = t; i < BUCKETS; i += 256)
                bbase[i] = atomicAdd(&bcursor[i], hist[i]);
            __syncthreads();
            #pragma unroll
            for (int i = 0; i < 8; ++i) {
                const int pos = atomicAdd(&bbase[bu[i]], 1);
                pairs[pos] = make_int2(src[i], dst[i]);
            }
            __syncthreads();
        }
        return;
    }

    const int wave = t >> 6, lane = t & 63;
    const int row0 = (b >> 1) * BM;
    const int lr = lane & 15, lq = lane >> 4;

    f32x4 acc[4];
    #pragma unroll
    for (int j = 0; j < 4; ++j) acc[j] = (f32x4){0.f, 0.f, 0.f, 0.f};

    auto stageA = [&](char* ldsa, const float* __restrict__ A, const int KD, const int k0) {
        #pragma unroll
        for (int p = 0; p < 4; ++p) {
            const int P = p * 4096 + t * 16;
            const int row = P >> 8;
            const int kk = ((P & 255) ^ ((row & 7) << 4)) >> 2;
            const int gk = min(k0 + kk, KD - 4);
            const int gr = min(row0 + row, NN - 1);
            __builtin_amdgcn_global_load_lds(
                (const __attribute__((address_space(1))) void*)(A + (long)gr * KD + gk),
                (__attribute__((address_space(3))) void*)(ldsa + P), 16, 0, 2 /*NT*/);
        }
    };
    auto stageB = [&](char* ldsb, const ushort_t* __restrict__ WT, const int k0) {
        #pragma unroll
        for (int p = 0; p < 2; ++p) {
            const int P = p * 4096 + t * 16;
            const int row = P >> 7;
            const int kkb = (P & 127) ^ ((row & 7) << 4);
            __builtin_amdgcn_global_load_lds(
                (const __attribute__((address_space(1))) void*)(WT + (long)row * KP + k0 + (kkb >> 1)),
                (__attribute__((address_space(3))) void*)(ldsb + P), 16, 0, 0);
        }
    };
    auto compute = [&](const char* ldsa, const char* ldsb) {
        #pragma unroll
        for (int ks = 0; ks < 2; ++ks) {
            const int ra = wave * 16 + lr;
            const int ka = ks * 128 + lq * 32;
            const int xa = (ra & 7) << 4;
            const float4 c0 = *(const float4*)(ldsa + ra * 256 + (ka ^ xa));
            const float4 c1 = *(const float4*)(ldsa + ra * 256 + ((ka + 16) ^ xa));
            const bf16x8 af = cvt8(c0, c1);
            bf16x8 bfr[4];
            #pragma unroll
            for (int cf = 0; cf < 4; ++cf) {
                const int col = cf * 16 + lr;
                const int kb = ks * 64 + lq * 16;
                bfr[cf] = *(const bf16x8*)(ldsb + col * 128 + (kb ^ ((col & 7) << 4)));
            }
            #pragma unroll
            for (int cf = 0; cf < 4; ++cf)
                acc[cf] = __builtin_amdgcn_mfma_f32_16x16x32_bf16(
                    af, bfr[cf], acc[cf], 0, 0, 0);
        }
    };

    auto phase = [&](const float* __restrict__ A, const ushort_t* __restrict__ WT,
                     auto KD_, auto NT_) {
        constexpr int KD = decltype(KD_)::value;
        constexpr int NT = decltype(NT_)::value;
        stageA((char*)As0, A, KD, 0);  stageB((char*)Bs0, WT, 0);
        stageA((char*)As1, A, KD, 64); stageB((char*)Bs1, WT, 64);
        #pragma unroll
        for (int kt = 0; kt < NT; ++kt) {
            if (kt == NT - 1) asm volatile("s_waitcnt vmcnt(0)" ::: "memory");
            else              asm volatile("s_waitcnt vmcnt(6)" ::: "memory");
            __builtin_amdgcn_s_barrier();        // chunk kt fully landed for all waves
            __builtin_amdgcn_sched_barrier(0);
            if (kt & 1) compute((const char*)As1, (const char*)Bs1);
            else        compute((const char*)As0, (const char*)Bs0);
            __builtin_amdgcn_sched_barrier(0);
            __builtin_amdgcn_s_barrier();        // all waves done reading buf[kt&1]
            if (kt + 2 < NT) {
                if (kt & 1) { stageA((char*)As1, A, KD, (kt + 2) * 64); stageB((char*)Bs1, WT, (kt + 2) * 64); }
                else        { stageA((char*)As0, A, KD, (kt + 2) * 64); stageB((char*)Bs0, WT, (kt + 2) * 64); }
            }
        }
    };

    phase(x, WfxT, IC<K_FEAT>{}, IC<8>{});
    phase(txt, WtxT, IC<K_TEXT>{}, IC<6>{});

    // epilogue: D frag layout col=lane&15, row=(lane>>4)*4+reg; store UNSCALED bf16
    #pragma unroll
    for (int reg = 0; reg < 4; ++reg) {
        const int r = row0 + wave * 16 + lq * 4 + reg;
        if (r < NN) {
            #pragma unroll
            for (int cf = 0; cf < 4; ++cf) {
                const int c = cf * 16 + lr;
                u1b[(long)r * H + c] = f2bf(acc[cf][reg] + bpre[c]);
            }
        }
    }
}

// ---------------- sort pass-2: per-256-node-bucket LDS counting sort ----------
// 392 blocks, 17KB LDS each -> good occupancy. Atomics in LDS; linear global write.
__global__ __launch_bounds__(256)
void sortp2_k(const int2* __restrict__ pairs, const int* __restrict__ bcursor,
              const int* __restrict__ row_start, int* __restrict__ src_sorted) {
    __shared__ int lcur[256];
    __shared__ int lout[BCAP];
    const int bu = blockIdx.x;
    const int t = threadIdx.x;
    const int nbase = bu << 8;
    const int r0 = row_start[nbase];
    const int cnt = bcursor[bu] - bu * BCAP;
    lcur[t] = row_start[nbase + t] - r0;
    __syncthreads();
    for (int i = t; i < cnt; i += 256) {
        const int2 pr = pairs[bu * BCAP + i];
        const int p = atomicAdd(&lcur[pr.y & 255], 1);
        lout[p] = pr.x;                           // p < cnt <= BCAP
    }
    __syncthreads();
    for (int i = t; i < cnt; i += 256)
        src_sorted[r0 + i] = lout[i];
}

// ---------------- layer1: CSR gather (8 lanes/node) w/ per-edge dinv[src] + relu + 64->7 ----
__global__ __launch_bounds__(256)
void layer1_csr_k(const int* __restrict__ row_start, const int* __restrict__ deg,
                  const int* __restrict__ src_sorted, const ushort_t* __restrict__ u1b,
                  const float* __restrict__ dinv, const float* __restrict__ b1,
                  const float* __restrict__ w2, float* __restrict__ u2) {
    const int t = threadIdx.x;
    const int lane = t & 63;
    const int g = lane >> 3;
    const int c8 = lane & 7;
    const int node = blockIdx.x * 32 + (t >> 6) * 8 + g;
    if (node >= NN) return;
    const int rs = row_start[node];
    const int dg = deg[node];
    const float di = dinv[node];

    float acc8[8];
    {
        const bf16x8 v = *(const bf16x8*)(u1b + (long)node * H + c8 * 8);
        #pragma unroll
        for (int c = 0; c < 8; ++c) acc8[c] = di * bf2f((ushort_t)v[c]);   // self * dinv[node]
    }
    int j = 0;
    for (; j + 4 <= dg; j += 4) {
        const int s0 = src_sorted[rs + j];
        const int s1 = src_sorted[rs + j + 1];
        const int s2 = src_sorted[rs + j + 2];
        const int s3 = src_sorted[rs + j + 3];
        const float w0 = dinv[s0], w1_ = dinv[s1], w2_ = dinv[s2], w3 = dinv[s3];
        const bf16x8 v0 = *(const bf16x8*)(u1b + (long)s0 * H + c8 * 8);
        const bf16x8 v1 = *(const bf16x8*)(u1b + (long)s1 * H + c8 * 8);
        const bf16x8 v2 = *(const bf16x8*)(u1b + (long)s2 * H + c8 * 8);
        const bf16x8 v3 = *(const bf16x8*)(u1b + (long)s3 * H + c8 * 8);
        #pragma unroll
        for (int c = 0; c < 8; ++c)
            acc8[c] += (w0 * bf2f((ushort_t)v0[c]) + w1_ * bf2f((ushort_t)v1[c]))
                     + (w2_ * bf2f((ushort_t)v2[c]) + w3 * bf2f((ushort_t)v3[c]));
    }
    for (; j < dg; ++j) {
        const int s0 = src_sorted[rs + j];
        const float w0 = dinv[s0];
        const bf16x8 v0 = *(const bf16x8*)(u1b + (long)s0 * H + c8 * 8);
        #pragma unroll
        for (int c = 0; c < 8; ++c) acc8[c] += w0 * bf2f((ushort_t)v0[c]);
    }
    float h[8];
    #pragma unroll
    for (int c = 0; c < 8; ++c)
        h[c] = fmaxf(fmaf(di, acc8[c], b1[c8 * 8 + c]), 0.f);
    #pragma unroll
    for (int jj = 0; jj < 7; ++jj) {
        float s = 0.f;
        #pragma unroll
        for (int c = 0; c < 8; ++c)
            s = fmaf(h[c], w2[(c8 * 8 + c) * 7 + jj], s);
        s += __shfl_xor(s, 1, 64);
        s += __shfl_xor(s, 2, 64);
        s += __shfl_xor(s, 4, 64);
        if (c8 == jj) u2[node * 8 + jj] = di * s;
    }
}

// ---------------- layer2: CSR gather-aggregate + final transform ----------------
__global__ __launch_bounds__(256)
void layer2_csr_k(const int* __restrict__ row_start, const int* __restrict__ deg,
                  const int* __restrict__ src_sorted, const float* __restrict__ u2,
                  const float* __restrict__ dinv, const float* __restrict__ b2,
                  float* __restrict__ out) {
    const int t = threadIdx.x;
    const int c = t & 7;
    const int node = blockIdx.x * 32 + (t >> 3);
    if (node >= NN) return;
    const int rs = row_start[node];
    const int dg = deg[node];
    float acc = (c < 7) ? u2[node * 8 + c] : 0.f;   // self
    int j = 0;
    for (; j + 4 <= dg; j += 4) {
        const int s0 = src_sorted[rs + j];
        const int s1 = src_sorted[rs + j + 1];
        const int s2 = src_sorted[rs + j + 2];
        const int s3 = src_sorted[rs + j + 3];
        if (c < 7) {
            acc += u2[s0 * 8 + c];
            acc += u2[s1 * 8 + c];
            acc += u2[s2 * 8 + c];
            acc += u2[s3 * 8 + c];
        }
    }
    for (; j < dg; ++j) {
        const int s = src_sorted[rs + j];
        if (c < 7) acc += u2[s * 8 + c];
    }
    if (c < 7) out[node * 7 + c] = dinv[node] * acc + b2[c];
}

extern "C" void kernel_launch(void* const* d_in, const int* in_sizes, int n_in,
                              void* d_out, int out_size, void* d_ws, size_t ws_size,
                              hipStream_t stream) {
    const float* x      = (const float*)d_in[0];
    const float* txt    = (const float*)d_in[1];
    const int*   ei     = (const int*)d_in[2];
    const float* w_feat = (const float*)d_in[3];
    const float* b_feat = (const float*)d_in[4];
    const float* w_text = (const float*)d_in[5];
    const float* b_text = (const float*)d_in[6];
    const float* w1     = (const float*)d_in[7];
    const float* b1     = (const float*)d_in[8];
    const float* w2     = (const float*)d_in[9];
    const float* b2     = (const float*)d_in[10];
    float* out = (float*)d_out;

    char* p = (char*)d_ws;
    auto alloc = [&](size_t bytes) {
        char* r = p;
        p += (bytes + 255) & ~(size_t)255;
        return r;
    };
    ushort_t* WfxT = (ushort_t*)alloc((size_t)H * KP * 2);
    ushort_t* WtxT = (ushort_t*)alloc((size_t)H * KP * 2);
    float* bpre = (float*)alloc(H * 4);
    int*   deg  = (int*)alloc((size_t)NNP * 4);
    float* dinv = (float*)alloc((size_t)NNP * 4);
    int*   row_start = (int*)alloc((size_t)NNP * 4);
    int*   bcursor   = (int*)alloc((size_t)BUCKETS * 4);
    int2*  pairs     = (int2*)alloc((size_t)BUCKETS * BCAP * 8);
    int*   src_sorted = (int*)alloc((size_t)NE * 4);
    ushort_t* u1b = (ushort_t*)alloc((size_t)NN * H * 2);
    float* u2   = (float*)alloc((size_t)NN * 8 * 4);

    hipMemsetAsync(deg, 0, (size_t)NNP * 4, stream);

    prep_k<<<FUSE_BLOCKS, 256, 0, stream>>>(w_feat, b_feat, w_text, b_text, w1,
                                            WfxT, WtxT, bpre, bcursor);
    gemm_sort_k<<<2 * GEMM_GRID, 256, 0, stream>>>(x, txt, WfxT, WtxT, bpre, u1b,
                                                   ei, bcursor, deg, pairs);
    offsets_k<<<SCAN_BLOCKS, 256, 0, stream>>>(deg, row_start, dinv);
    sortp2_k<<<BUCKETS, 256, 0, stream>>>(pairs, bcursor, row_start, src_sorted);
    layer1_csr_k<<<(NN + 31) / 32, 256, 0, stream>>>(row_start, deg, src_sorted, u1b,
                                                     dinv, b1, w2, u2);
    layer2_csr_k<<<(NN + 31) / 32, 256, 0, stream>>>(row_start, deg, src_sorted, u2,
                                                     dinv, b2, out);
}

// Round 18
// 214.878 us; speedup vs baseline: 1.4455x; 1.1846x over previous
//
#include <hip/hip_runtime.h>

#define NN 100000
#define NNP 100352               // 392 * 256 (padded node count)
#define NE 1280000
#define K_FEAT 500
#define K_TEXT 384
#define KP 512
#define H 64
#define BM 64
#define GEMM_GRID 1563           // (NN+BM-1)/BM
#define FUSE_BLOCKS 257
#define SORT_CHUNK 2048
#define NCHUNKS 625              // NE / SORT_CHUNK
#define BUCKETS 392              // 256-node dst buckets
#define BCAP 4096                // static region capacity per bucket (mean 3277, +14 sigma)

typedef unsigned short ushort_t;
typedef __attribute__((ext_vector_type(8))) short bf16x8;
typedef __attribute__((ext_vector_type(4))) float f32x4;

template <int V> struct IC { static constexpr int value = V; };

__device__ __forceinline__ ushort_t f2bf(float f) {
    union { float f; unsigned int u; } v; v.f = f;
    unsigned int r = (v.u + 0x7FFFu + ((v.u >> 16) & 1u)) >> 16;  // RNE
    return (ushort_t)r;
}

__device__ __forceinline__ float bf2f(ushort_t u) {
    union { unsigned int i; float f; } v; v.i = ((unsigned int)u) << 16; return v.f;
}

// pack 8 f32 -> 8 bf16 via hardware cvt_pk (RNE)
__device__ __forceinline__ bf16x8 cvt8(float4 a, float4 b) {
    union { bf16x8 v; unsigned int w[4]; } u;
    asm("v_cvt_pk_bf16_f32 %0, %1, %2" : "=v"(u.w[0]) : "v"(a.x), "v"(a.y));
    asm("v_cvt_pk_bf16_f32 %0, %1, %2" : "=v"(u.w[1]) : "v"(a.z), "v"(a.w));
    asm("v_cvt_pk_bf16_f32 %0, %1, %2" : "=v"(u.w[2]) : "v"(b.x), "v"(b.y));
    asm("v_cvt_pk_bf16_f32 %0, %1, %2" : "=v"(u.w[3]) : "v"(b.z), "v"(b.w));
    return u.v;
}

// ---------------- preprocessing: weight fusion only (+ bcursor static-region init) ----------
__global__ void prep_k(const float* __restrict__ wf, const float* __restrict__ bf,
                       const float* __restrict__ wt, const float* __restrict__ bt,
                       const float* __restrict__ w1,
                       ushort_t* __restrict__ WfxT, ushort_t* __restrict__ WtxT,
                       float* __restrict__ bpre, int* __restrict__ bcursor) {
    if (blockIdx.x == 0) {
        for (int i = threadIdx.x; i < BUCKETS; i += 256) bcursor[i] = i * BCAP;
    }
    const int idx = blockIdx.x * 256 + threadIdx.x;
    const int T1 = H * KP;
    const int T2 = 2 * T1;
    if (idx < T1) {
        const int c = idx >> 9, k = idx & 511;
        float s = 0.f;
        if (k < K_FEAT) {
            #pragma unroll 8
            for (int u = 0; u < 64; ++u) s = fmaf(wf[k * 64 + u], w1[u * 64 + c], s);
        }
        WfxT[idx] = f2bf(s);
    } else if (idx < T2) {
        const int r = idx - T1;
        const int c = r >> 9, k = r & 511;
        float s = 0.f;
        if (k < K_TEXT) {
            #pragma unroll 8
            for (int u = 0; u < 64; ++u) s = fmaf(wt[k * 64 + u], w1[(64 + u) * 64 + c], s);
        }
        WtxT[r] = f2bf(s);
    } else if (idx < T2 + H) {
        const int j = idx - T2;
        float s = 0.f;
        for (int u = 0; u < 64; ++u) s = fmaf(bf[u], w1[u * 64 + j], s);
        for (int u = 0; u < 64; ++u) s = fmaf(bt[u], w1[(64 + u) * 64 + j], s);
        bpre[j] = s;
    }
}

// ---------------- FAT kernel: gemm1 (odd blocks) ∥ sort p1 binning (even blocks) ------------
// gemm1: u1b[N,64] = bf16(x@Wfx + txt@Wtx + bpre)  -- UNSCALED (dinv applied in layer1).
// sort-p1 bins edges by dst>>8 into STATIC bucket regions (b*BCAP) -- no deg, no CSR dep.
__global__ __launch_bounds__(256)
void gemm_sort_k(const float* __restrict__ x, const float* __restrict__ txt,
                 const ushort_t* __restrict__ WfxT, const ushort_t* __restrict__ WtxT,
                 const float* __restrict__ bpre, ushort_t* __restrict__ u1b,
                 const int* __restrict__ ei, int* __restrict__ bcursor,
                 int2* __restrict__ pairs) {
    __shared__ float As0[BM * 64], As1[BM * 64];      // 16 KB each, 256B rows, swizzled
    __shared__ ushort_t Bs0[H * 64], Bs1[H * 64];     // 8 KB each, 128B rows, swizzled
    const int b = blockIdx.x;
    const int t = threadIdx.x;

    if ((b & 1) == 0) {
        // ---------------- sort pass-1: LDS-binned static-region append ----------------
        int* hist = (int*)As0;          // [BUCKETS]
        int* bbase = hist + 512;        // [BUCKETS]
        for (int chunk = b >> 1; chunk < NCHUNKS; chunk += GEMM_GRID) {
            const int e0 = chunk * SORT_CHUNK + t * 8;
            int4 s0 = *(const int4*)&ei[e0];
            int4 s1 = *(const int4*)&ei[e0 + 4];
            int4 d0 = *(const int4*)&ei[NE + e0];
            int4 d1 = *(const int4*)&ei[NE + e0 + 4];
            const int src[8] = {s0.x, s0.y, s0.z, s0.w, s1.x, s1.y, s1.z, s1.w};
            const int dst[8] = {d0.x, d0.y, d0.z, d0.w, d1.x, d1.y, d1.z, d1.w};
            for (int i = t; i < BUCKETS; i += 256) hist[i] = 0;
            __syncthreads();
            int bu[8];
            #pragma unroll
            for (int i = 0; i < 8; ++i) {
                bu[i] = dst[i] >> 8;
                atomicAdd(&hist[bu[i]], 1);
            }
            __syncthreads();
            for (int i = t; i < BUCKETS; i += 256)
                bbase[i] = atomicAdd(&bcursor[i], hist[i]);
            __syncthreads();
            #pragma unroll
            for (int i = 0; i < 8; ++i) {
                const int pos = atomicAdd(&bbase[bu[i]], 1);
                pairs[pos] = make_int2(src[i], dst[i]);
            }
            __syncthreads();
        }
        return;
    }

    const int wave = t >> 6, lane = t & 63;
    const int row0 = (b >> 1) * BM;
    const int lr = lane & 15, lq = lane >> 4;

    f32x4 acc[4];
    #pragma unroll
    for (int j = 0; j < 4; ++j) acc[j] = (f32x4){0.f, 0.f, 0.f, 0.f};

    auto stageA = [&](char* ldsa, const float* __restrict__ A, const int KD, const int k0) {
        #pragma unroll
        for (int p = 0; p < 4; ++p) {
            const int P = p * 4096 + t * 16;
            const int row = P >> 8;
            const int kk = ((P & 255) ^ ((row & 7) << 4)) >> 2;
            const int gk = min(k0 + kk, KD - 4);
            const int gr = min(row0 + row, NN - 1);
            __builtin_amdgcn_global_load_lds(
                (const __attribute__((address_space(1))) void*)(A + (long)gr * KD + gk),
                (__attribute__((address_space(3))) void*)(ldsa + P), 16, 0, 2 /*NT*/);
        }
    };
    auto stageB = [&](char* ldsb, const ushort_t* __restrict__ WT, const int k0) {
        #pragma unroll
        for (int p = 0; p < 2; ++p) {
            const int P = p * 4096 + t * 16;
            const int row = P >> 7;
            const int kkb = (P & 127) ^ ((row & 7) << 4);
            __builtin_amdgcn_global_load_lds(
                (const __attribute__((address_space(1))) void*)(WT + (long)row * KP + k0 + (kkb >> 1)),
                (__attribute__((address_space(3))) void*)(ldsb + P), 16, 0, 0);
        }
    };
    auto compute = [&](const char* ldsa, const char* ldsb) {
        #pragma unroll
        for (int ks = 0; ks < 2; ++ks) {
            const int ra = wave * 16 + lr;
            const int ka = ks * 128 + lq * 32;
            const int xa = (ra & 7) << 4;
            const float4 c0 = *(const float4*)(ldsa + ra * 256 + (ka ^ xa));
            const float4 c1 = *(const float4*)(ldsa + ra * 256 + ((ka + 16) ^ xa));
            const bf16x8 af = cvt8(c0, c1);
            bf16x8 bfr[4];
            #pragma unroll
            for (int cf = 0; cf < 4; ++cf) {
                const int col = cf * 16 + lr;
                const int kb = ks * 64 + lq * 16;
                bfr[cf] = *(const bf16x8*)(ldsb + col * 128 + (kb ^ ((col & 7) << 4)));
            }
            #pragma unroll
            for (int cf = 0; cf < 4; ++cf)
                acc[cf] = __builtin_amdgcn_mfma_f32_16x16x32_bf16(
                    af, bfr[cf], acc[cf], 0, 0, 0);
        }
    };

    auto phase = [&](const float* __restrict__ A, const ushort_t* __restrict__ WT,
                     auto KD_, auto NT_) {
        constexpr int KD = decltype(KD_)::value;
        constexpr int NT = decltype(NT_)::value;
        stageA((char*)As0, A, KD, 0);  stageB((char*)Bs0, WT, 0);
        stageA((char*)As1, A, KD, 64); stageB((char*)Bs1, WT, 64);
        #pragma unroll
        for (int kt = 0; kt < NT; ++kt) {
            if (kt == NT - 1) asm volatile("s_waitcnt vmcnt(0)" ::: "memory");
            else              asm volatile("s_waitcnt vmcnt(6)" ::: "memory");
            __builtin_amdgcn_s_barrier();        // chunk kt fully landed for all waves
            __builtin_amdgcn_sched_barrier(0);
            if (kt & 1) compute((const char*)As1, (const char*)Bs1);
            else        compute((const char*)As0, (const char*)Bs0);
            __builtin_amdgcn_sched_barrier(0);
            __builtin_amdgcn_s_barrier();        // all waves done reading buf[kt&1]
            if (kt + 2 < NT) {
                if (kt & 1) { stageA((char*)As1, A, KD, (kt + 2) * 64); stageB((char*)Bs1, WT, (kt + 2) * 64); }
                else        { stageA((char*)As0, A, KD, (kt + 2) * 64); stageB((char*)Bs0, WT, (kt + 2) * 64); }
            }
        }
    };

    phase(x, WfxT, IC<K_FEAT>{}, IC<8>{});
    phase(txt, WtxT, IC<K_TEXT>{}, IC<6>{});

    // epilogue: D frag layout col=lane&15, row=(lane>>4)*4+reg; store UNSCALED bf16
    #pragma unroll
    for (int reg = 0; reg < 4; ++reg) {
        const int r = row0 + wave * 16 + lq * 4 + reg;
        if (r < NN) {
            #pragma unroll
            for (int cf = 0; cf < 4; ++cf) {
                const int c = cf * 16 + lr;
                u1b[(long)r * H + c] = f2bf(acc[cf][reg] + bpre[c]);
            }
        }
    }
}

// ---------------- sort pass-2 = CSR factory: per-bucket histogram -> deg/dinv/row_start,
// then LDS counting sort -> linear src_sorted. Bucket base r0 from prefix over bcursor sizes.
__global__ __launch_bounds__(256)
void sortp2_k(const int2* __restrict__ pairs, const int* __restrict__ bcursor,
              int* __restrict__ deg, float* __restrict__ dinv,
              int* __restrict__ row_start, int* __restrict__ src_sorted) {
    __shared__ int lhist[256];
    __shared__ int lcur[256];
    __shared__ int lout[BCAP];
    __shared__ int ws[4];
    const int bu = blockIdx.x;
    const int t = threadIdx.x;
    const int nbase = bu << 8;
    const int cnt = bcursor[bu] - bu * BCAP;
    // r0 = sum of bucket sizes 0..bu-1 (bcursor is L2-hot, 392 ints)
    int pre = 0;
    for (int i = t; i < bu; i += 256) pre += bcursor[i] - i * BCAP;
    #pragma unroll
    for (int m = 1; m < 64; m <<= 1) pre += __shfl_xor(pre, m, 64);
    if ((t & 63) == 0) ws[t >> 6] = pre;
    lhist[t] = 0;
    __syncthreads();
    const int r0 = ws[0] + ws[1] + ws[2] + ws[3];
    // histogram pass
    for (int i = t; i < cnt; i += 256)
        atomicAdd(&lhist[pairs[bu * BCAP + i].y & 255], 1);
    __syncthreads();
    // exclusive scan of lhist -> lcur (标准 256-scan via shared)
    const int dg = lhist[t];
    int run = dg;
    lcur[t] = run;
    __syncthreads();
    #pragma unroll
    for (int off = 1; off < 256; off <<= 1) {
        int v = (t >= off) ? lcur[t - off] : 0;
        __syncthreads();
        lcur[t] += v;
        __syncthreads();
    }
    const int excl = lcur[t] - dg;
    // emit CSR metadata
    deg[nbase + t] = dg;
    dinv[nbase + t] = rsqrtf((float)dg + 1.0f);
    row_start[nbase + t] = r0 + excl;
    __syncthreads();
    lcur[t] = excl;
    __syncthreads();
    // counting-sort pass
    for (int i = t; i < cnt; i += 256) {
        const int2 pr = pairs[bu * BCAP + i];
        const int p = atomicAdd(&lcur[pr.y & 255], 1);
        lout[p] = pr.x;
    }
    __syncthreads();
    for (int i = t; i < cnt; i += 256)
        src_sorted[r0 + i] = lout[i];
}

// ---------------- layer1: CSR gather (8 lanes/node) w/ per-edge dinv[src] + relu + 64->7 ----
__global__ __launch_bounds__(256)
void layer1_csr_k(const int* __restrict__ row_start, const int* __restrict__ deg,
                  const int* __restrict__ src_sorted, const ushort_t* __restrict__ u1b,
                  const float* __restrict__ dinv, const float* __restrict__ b1,
                  const float* __restrict__ w2, float* __restrict__ u2) {
    const int t = threadIdx.x;
    const int lane = t & 63;
    const int g = lane >> 3;
    const int c8 = lane & 7;
    const int node = blockIdx.x * 32 + (t >> 6) * 8 + g;
    if (node >= NN) return;
    const int rs = row_start[node];
    const int dg = deg[node];
    const float di = dinv[node];

    float acc8[8];
    {
        const bf16x8 v = *(const bf16x8*)(u1b + (long)node * H + c8 * 8);
        #pragma unroll
        for (int c = 0; c < 8; ++c) acc8[c] = di * bf2f((ushort_t)v[c]);   // self * dinv[node]
    }
    int j = 0;
    for (; j + 4 <= dg; j += 4) {
        const int s0 = src_sorted[rs + j];
        const int s1 = src_sorted[rs + j + 1];
        const int s2 = src_sorted[rs + j + 2];
        const int s3 = src_sorted[rs + j + 3];
        const float w0 = dinv[s0], w1_ = dinv[s1], w2_ = dinv[s2], w3 = dinv[s3];
        const bf16x8 v0 = *(const bf16x8*)(u1b + (long)s0 * H + c8 * 8);
        const bf16x8 v1 = *(const bf16x8*)(u1b + (long)s1 * H + c8 * 8);
        const bf16x8 v2 = *(const bf16x8*)(u1b + (long)s2 * H + c8 * 8);
        const bf16x8 v3 = *(const bf16x8*)(u1b + (long)s3 * H + c8 * 8);
        #pragma unroll
        for (int c = 0; c < 8; ++c)
            acc8[c] += (w0 * bf2f((ushort_t)v0[c]) + w1_ * bf2f((ushort_t)v1[c]))
                     + (w2_ * bf2f((ushort_t)v2[c]) + w3 * bf2f((ushort_t)v3[c]));
    }
    for (; j < dg; ++j) {
        const int s0 = src_sorted[rs + j];
        const float w0 = dinv[s0];
        const bf16x8 v0 = *(const bf16x8*)(u1b + (long)s0 * H + c8 * 8);
        #pragma unroll
        for (int c = 0; c < 8; ++c) acc8[c] += w0 * bf2f((ushort_t)v0[c]);
    }
    float h[8];
    #pragma unroll
    for (int c = 0; c < 8; ++c)
        h[c] = fmaxf(fmaf(di, acc8[c], b1[c8 * 8 + c]), 0.f);
    #pragma unroll
    for (int jj = 0; jj < 7; ++jj) {
        float s = 0.f;
        #pragma unroll
        for (int c = 0; c < 8; ++c)
            s = fmaf(h[c], w2[(c8 * 8 + c) * 7 + jj], s);
        s += __shfl_xor(s, 1, 64);
        s += __shfl_xor(s, 2, 64);
        s += __shfl_xor(s, 4, 64);
        if (c8 == jj) u2[node * 8 + jj] = di * s;
    }
}

// ---------------- layer2: CSR gather-aggregate + final transform ----------------
__global__ __launch_bounds__(256)
void layer2_csr_k(const int* __restrict__ row_start, const int* __restrict__ deg,
                  const int* __restrict__ src_sorted, const float* __restrict__ u2,
                  const float* __restrict__ dinv, const float* __restrict__ b2,
                  float* __restrict__ out) {
    const int t = threadIdx.x;
    const int c = t & 7;
    const int node = blockIdx.x * 32 + (t >> 3);
    if (node >= NN) return;
    const int rs = row_start[node];
    const int dg = deg[node];
    float acc = (c < 7) ? u2[node * 8 + c] : 0.f;   // self
    int j = 0;
    for (; j + 4 <= dg; j += 4) {
        const int s0 = src_sorted[rs + j];
        const int s1 = src_sorted[rs + j + 1];
        const int s2 = src_sorted[rs + j + 2];
        const int s3 = src_sorted[rs + j + 3];
        if (c < 7) {
            acc += u2[s0 * 8 + c];
            acc += u2[s1 * 8 + c];
            acc += u2[s2 * 8 + c];
            acc += u2[s3 * 8 + c];
        }
    }
    for (; j < dg; ++j) {
        const int s = src_sorted[rs + j];
        if (c < 7) acc += u2[s * 8 + c];
    }
    if (c < 7) out[node * 7 + c] = dinv[node] * acc + b2[c];
}

extern "C" void kernel_launch(void* const* d_in, const int* in_sizes, int n_in,
                              void* d_out, int out_size, void* d_ws, size_t ws_size,
                              hipStream_t stream) {
    const float* x      = (const float*)d_in[0];
    const float* txt    = (const float*)d_in[1];
    const int*   ei     = (const int*)d_in[2];
    const float* w_feat = (const float*)d_in[3];
    const float* b_feat = (const float*)d_in[4];
    const float* w_text = (const float*)d_in[5];
    const float* b_text = (const float*)d_in[6];
    const float* w1     = (const float*)d_in[7];
    const float* b1     = (const float*)d_in[8];
    const float* w2     = (const float*)d_in[9];
    const float* b2     = (const float*)d_in[10];
    float* out = (float*)d_out;

    char* p = (char*)d_ws;
    auto alloc = [&](size_t bytes) {
        char* r = p;
        p += (bytes + 255) & ~(size_t)255;
        return r;
    };
    ushort_t* WfxT = (ushort_t*)alloc((size_t)H * KP * 2);
    ushort_t* WtxT = (ushort_t*)alloc((size_t)H * KP * 2);
    float* bpre = (float*)alloc(H * 4);
    int*   deg  = (int*)alloc((size_t)NNP * 4);
    float* dinv = (float*)alloc((size_t)NNP * 4);
    int*   row_start = (int*)alloc((size_t)NNP * 4);
    int*   bcursor   = (int*)alloc((size_t)BUCKETS * 4);
    int2*  pairs     = (int2*)alloc((size_t)BUCKETS * BCAP * 8);
    int*   src_sorted = (int*)alloc((size_t)NE * 4);
    ushort_t* u1b = (ushort_t*)alloc((size_t)NN * H * 2);
    float* u2   = (float*)alloc((size_t)NN * 8 * 4);

    prep_k<<<FUSE_BLOCKS, 256, 0, stream>>>(w_feat, b_feat, w_text, b_text, w1,
                                            WfxT, WtxT, bpre, bcursor);
    gemm_sort_k<<<2 * GEMM_GRID, 256, 0, stream>>>(x, txt, WfxT, WtxT, bpre, u1b,
                                                   ei, bcursor, pairs);
    sortp2_k<<<BUCKETS, 256, 0, stream>>>(pairs, bcursor, deg, dinv, row_start, src_sorted);
    layer1_csr_k<<<(NN + 31) / 32, 256, 0, stream>>>(row_start, deg, src_sorted, u1b,
                                                     dinv, b1, w2, u2);
    layer2_csr_k<<<(NN + 31) / 32, 256, 0, stream>>>(row_start, deg, src_sorted, u2,
                                                     dinv, b2, out);
}